// Round 10
// baseline (219.795 us; speedup 1.0000x reference)
//
#include <hip/hip_runtime.h>
#include <cstdint>
#include <cstddef>

// ---------------------------------------------------------------------------
// MHA: out = softmax(causal(mask((XWq)(XWk)^T/8))) (XWv) Wo + biases
// B=2, T=2048, D=1024, H=16, dk=64. bf16 MFMA, fp32 accumulate.
// R17 (attn LDS-redundancy halving; R16 split REVERTED):
//   Resource account: each wave read the FULL 8KB K + 8KB V tile -> 64KB LDS
//   reads per block-tile ~ 750cy; x4 resident blocks = ~3kcy/tile = the
//   observed interval. attn is LDS-read-BW bound.
//   Fix: wave (qh,kh) owns 32 queries x 32 keys: K reads 2 groups (kh half),
//   V reads granules kh*4+kg -> 8 ds_reads/wave-tile (was 16), block-tile
//   LDS reads 64->32KB. MFMA/exp2/pack counts unchanged. Once per block:
//   cross-kh O/l combine via Ks-as-scratch (padded stride 68).
//   __launch_bounds__(256,4) pins VGPR<=128 so 4 blocks/CU stay resident.
//   Carried (R15): K tbuf depth-2 + V dbuf depth-1 (40KB exactly), raw
//   s_barrier + counted vmcnt(2), unroll-6 compile-time buffers, longest-
//   first qc map, Q pre-scaled (exp2 direct), denom on matrix pipe, cvt_pk
//   pack, setprio. GEMMs/cvt frozen at R9/R10 structure.
// ---------------------------------------------------------------------------

typedef __bf16 bf16x8 __attribute__((ext_vector_type(8)));
typedef float f32x4 __attribute__((ext_vector_type(4)));

#define MFMA(a, b, c) __builtin_amdgcn_mfma_f32_16x16x32_bf16((a), (b), (c), 0, 0, 0)

static constexpr int D_MODEL = 1024;
static constexpr int T_ = 2048;
static constexpr int M_TOK = 4096;   // B*T

__device__ __forceinline__ unsigned short f32_to_bf16(float f) {   // RNE
    union { float f; uint32_t u; } v; v.f = f;
    uint32_t u = v.u;
    uint32_t r = u + 0x7fffu + ((u >> 16) & 1u);
    return (unsigned short)(r >> 16);
}
// pack two f32 -> bf16x2 (low = a). Compiler emits v_cvt_pk_bf16_f32 (RNE).
__device__ __forceinline__ unsigned pk2(float a, float b) {
    union { __bf16 h[2]; unsigned u; } z;
    z.h[0] = (__bf16)a; z.h[1] = (__bf16)b;
    return z.u;
}

typedef __attribute__((address_space(1))) void* as1_ptr;
typedef __attribute__((address_space(3))) void* as3_ptr;
__device__ __forceinline__ void gload_lds16(const void* g, void* l) {
    // lane's 16B land at (wave-uniform l) + lane*16
    __builtin_amdgcn_global_load_lds((as1_ptr)(void*)g, (as3_ptr)l, 16, 0, 0);
}

// sigma: actual key (within 64) -> storage index matching PV MFMA k-slots.
__device__ __forceinline__ int keyperm(int k) {
    return (k & 32) | ((k & 12) << 1) | ((k & 16) >> 2) | (k & 3);
}

// --------------------------- fused fp32 -> bf16 convert ---------------------
// dst (float4 units): q[0,1M) k[1M,2M) v[2M,3M) Wq Wk Wv Wo [3M..4M)
__global__ __launch_bounds__(256) void cvt_all(
    const float* __restrict__ q, const float* __restrict__ k,
    const float* __restrict__ v, const float* __restrict__ wq,
    const float* __restrict__ wk, const float* __restrict__ wv,
    const float* __restrict__ wo, ushort4* __restrict__ dst) {
    int i = blockIdx.x * blockDim.x + threadIdx.x;
    constexpr int R = 1 << 20;        // 1M float4 per token tensor
    const float* s;
    int idx;
    if (i < 3 * R) {
        s = (i < R) ? q : (i < 2 * R) ? k : v;
        idx = i & (R - 1);
    } else {
        int j = i - 3 * R;
        int w = j >> 18;
        s = (w == 0) ? wq : (w == 1) ? wk : (w == 2) ? wv : wo;
        idx = j & ((1 << 18) - 1);
    }
    float4 f = ((const float4*)s)[idx];
    ushort4 o;
    o.x = (unsigned short)f32_to_bf16(f.x); o.y = (unsigned short)f32_to_bf16(f.y);
    o.z = (unsigned short)f32_to_bf16(f.z); o.w = (unsigned short)f32_to_bf16(f.w);
    dst[i] = o;
}

// --------------------------- GEMM: C = A @ W^T + bias -----------------------
// Tile 128 x (NT16*32), BK=32, 4 waves 2x2, global_load_lds(16B).
// Triple-buffered LDS, raw s_barrier + counted vmcnt(4): two stages always
// in flight; the barrier never drains the load queue (main loop).
// Granule swizzle: row has 4 16B-granules; physical g = logical ^ ((row>>1)&3)
// -> a wave's 64 b128 reads map bijectively onto 64 slots (2/bank, free).
// MODE 0: bf16 row-major [M][1024] (Q,K; SWAPPED epilogue -> ushort4 stores).
// MODE 2: bf16 [B][H][64][Tperm] (V; UNswapped, t sigma-permuted per 64-blk).
// MODE 3: f32 row-major [M][1024] (SWAPPED -> float4 stores).
// oscale: multiplies (acc + bias) -- used to pre-scale Q by log2(e)/sqrt(dk).
template<int MODE, int NT16>
__device__ __forceinline__ void gemm_body(
    const unsigned short* __restrict__ A, const unsigned short* __restrict__ W,
    const float* __restrict__ bias, void* __restrict__ outp,
    unsigned short* As, unsigned short* Ws, int bx, int by, float oscale)
{
    constexpr bool SWAP = (MODE != 2);
    constexpr int BKE = 32;                     // K elems per step
    constexpr int ASZ = 128 * BKE;              // ushorts per A buffer (8 KB)
    constexpr int WSZ = NT16 * 32 * BKE;        // ushorts per W buffer
    constexpr int AL = ASZ / (256 * 8);         // gloads/thread for A (=2)
    constexpr int WL = WSZ / (256 * 8);         // gloads/thread for W (=2 @NT16=4)
    constexpr int NKS = D_MODEL / BKE;          // 32
    const int tid = threadIdx.x;
    const int lane = tid & 63, wave = tid >> 6;
    const int wm = wave >> 1, wn = wave & 1;
    const int r16 = lane & 15, kg = lane >> 4;
    const int m_blk = by * 128, n_blk = bx * (NT16 * 32);

    // hoisted staging addresses: source pre-swizzled, LDS dest linear
    const unsigned short* Ap[AL]; unsigned short* Albase[AL];
    #pragma unroll
    for (int j = 0; j < AL; ++j) {
        int si = j * 256 + tid;
        int row = si >> 2, p = si & 3, g = p ^ ((row >> 1) & 3);
        Ap[j] = A + (size_t)(m_blk + row) * D_MODEL + g * 8;
        Albase[j] = As + (j * 256 + wave * 64) * 8;   // wave-uniform base
    }
    const unsigned short* Wp[WL]; unsigned short* Wlbase[WL];
    #pragma unroll
    for (int j = 0; j < WL; ++j) {
        int si = j * 256 + tid;
        int row = si >> 2, p = si & 3, g = p ^ ((row >> 1) & 3);
        Wp[j] = W + (size_t)(n_blk + row) * D_MODEL + g * 8;
        Wlbase[j] = Ws + (j * 256 + wave * 64) * 8;
    }

    // hoisted (loop-invariant) ds_read offsets
    int aoff[4], woff[NT16];
    #pragma unroll
    for (int mt = 0; mt < 4; ++mt) {
        int row = wm * 64 + mt * 16 + r16;
        aoff[mt] = row * BKE + ((kg ^ ((row >> 1) & 3)) * 8);
    }
    #pragma unroll
    for (int nt = 0; nt < NT16; ++nt) {
        int row = wn * (NT16 * 16) + nt * 16 + r16;
        woff[nt] = row * BKE + ((kg ^ ((row >> 1) & 3)) * 8);
    }

    f32x4 acc[4][NT16];
    #pragma unroll
    for (int mt = 0; mt < 4; ++mt)
        #pragma unroll
        for (int nt = 0; nt < NT16; ++nt) acc[mt][nt] = (f32x4){0, 0, 0, 0};

    auto stage = [&](int bb, int k0) {
        #pragma unroll
        for (int j = 0; j < AL; ++j)
            gload_lds16(Ap[j] + k0, Albase[j] + bb * ASZ);
        #pragma unroll
        for (int j = 0; j < WL; ++j)
            gload_lds16(Wp[j] + k0, Wlbase[j] + bb * WSZ);
    };

    // prologue: two stages in flight
    stage(0, 0);
    stage(1, BKE);
    int cb = 0;                                 // compute buffer = ks % 3
    for (int ks = 0; ks < NKS; ++ks) {
        // wait ONLY for stage(ks) (issued 2 steps ago); stage(ks+1) stays in
        // flight across the barrier. Last iter: drain.
        if (ks + 1 < NKS) asm volatile("s_waitcnt vmcnt(4)" ::: "memory");
        else              asm volatile("s_waitcnt vmcnt(0)" ::: "memory");
        __builtin_amdgcn_s_barrier();           // raw: no compiler vmcnt drain
        __builtin_amdgcn_sched_barrier(0);      // ds_reads must not hoist above
        if (ks + 2 < NKS) {
            int sb = cb + 2; if (sb >= 3) sb -= 3;
            stage(sb, (ks + 2) * BKE);          // buf freed by compute(ks-1)
        }
        const unsigned short* Asb = As + cb * ASZ;
        const unsigned short* Wsb = Ws + cb * WSZ;
        bf16x8 af[4], wf[NT16];
        #pragma unroll
        for (int mt = 0; mt < 4; ++mt)
            af[mt] = *(const bf16x8*)(Asb + aoff[mt]);
        #pragma unroll
        for (int nt = 0; nt < NT16; ++nt)
            wf[nt] = *(const bf16x8*)(Wsb + woff[nt]);
        #pragma unroll
        for (int mt = 0; mt < 4; ++mt)
            #pragma unroll
            for (int nt = 0; nt < NT16; ++nt)
                acc[mt][nt] = SWAP ? MFMA(wf[nt], af[mt], acc[mt][nt])
                                   : MFMA(af[mt], wf[nt], acc[mt][nt]);
        cb = (cb == 2) ? 0 : cb + 1;
    }

    if (MODE == 2) {
        // UNswapped C/D: lane holds m = kg*4+r (t, consecutive), n = r16 fixed.
        #pragma unroll
        for (int nt = 0; nt < NT16; ++nt) {
            int n = n_blk + wn * (NT16 * 16) + nt * 16 + r16;
            float bn = bias[n];
            int hh = n >> 6, dki = n & 63;
            #pragma unroll
            for (int mt = 0; mt < 4; ++mt) {
                int m0 = m_blk + wm * 64 + mt * 16 + kg * 4;
                int mp = (m0 & ~63) | keyperm(m0 & 63);   // sigma within 64-blk
                int bb = mp >> 11, ti = mp & 2047;
                ushort4 pk;
                pk.x = f32_to_bf16((acc[mt][nt][0] + bn) * oscale);
                pk.y = f32_to_bf16((acc[mt][nt][1] + bn) * oscale);
                pk.z = f32_to_bf16((acc[mt][nt][2] + bn) * oscale);
                pk.w = f32_to_bf16((acc[mt][nt][3] + bn) * oscale);
                *(ushort4*)((unsigned short*)outp +
                    ((size_t)(bb * 16 + hh) * 64 + dki) * 2048 + ti) = pk;
            }
        }
    } else {
        // SWAPPED C/D: lane holds n = kg*4+r (consecutive), m = r16 fixed.
        #pragma unroll
        for (int nt = 0; nt < NT16; ++nt) {
            int n0 = n_blk + wn * (NT16 * 16) + nt * 16 + kg * 4;
            float4 bn4 = *(const float4*)(bias + n0);
            #pragma unroll
            for (int mt = 0; mt < 4; ++mt) {
                int m = m_blk + wm * 64 + mt * 16 + r16;
                if (MODE == 3) {
                    float4 st;
                    st.x = (acc[mt][nt][0] + bn4.x) * oscale;
                    st.y = (acc[mt][nt][1] + bn4.y) * oscale;
                    st.z = (acc[mt][nt][2] + bn4.z) * oscale;
                    st.w = (acc[mt][nt][3] + bn4.w) * oscale;
                    *(float4*)((float*)outp + (size_t)m * D_MODEL + n0) = st;
                } else {
                    ushort4 pk;
                    pk.x = f32_to_bf16((acc[mt][nt][0] + bn4.x) * oscale);
                    pk.y = f32_to_bf16((acc[mt][nt][1] + bn4.y) * oscale);
                    pk.z = f32_to_bf16((acc[mt][nt][2] + bn4.z) * oscale);
                    pk.w = f32_to_bf16((acc[mt][nt][3] + bn4.w) * oscale);
                    *(ushort4*)((unsigned short*)outp + (size_t)m * D_MODEL + n0) = pk;
                }
            }
        }
    }
}

__global__ __launch_bounds__(256) void gemm_qkv(
    const unsigned short* __restrict__ qb, const unsigned short* __restrict__ kb,
    const unsigned short* __restrict__ vb, const unsigned short* __restrict__ Wqb,
    const unsigned short* __restrict__ Wkb, const unsigned short* __restrict__ Wvb,
    const float* __restrict__ bq, const float* __restrict__ bk, const float* __restrict__ bv,
    unsigned short* __restrict__ Qhp, unsigned short* __restrict__ Khp,
    unsigned short* __restrict__ Vtp)
{
    __shared__ __align__(16) unsigned short As[3 * 128 * 32];   // 24 KB tbuf
    __shared__ __align__(16) unsigned short Ws[3 * 128 * 32];   // 24 KB tbuf
    // Bijective XCD swizzle (grid 8x32x3, nwg=768): contiguous 96-chunks/XCD.
    int flat = blockIdx.x + (blockIdx.y << 3) + (blockIdx.z << 8);
    int w = (flat & 7) * 96 + (flat >> 3);
    int bx = w & 7, by = (w >> 3) & 31, z = w >> 8;
    const unsigned short* A = (z == 0) ? qb : (z == 1) ? kb : vb;
    const unsigned short* W = (z == 0) ? Wqb : (z == 1) ? Wkb : Wvb;
    const float* bias = (z == 0) ? bq : (z == 1) ? bk : bv;
    // Q stored pre-scaled by log2(e)/sqrt(dk): attn computes exp2(s) direct.
    float osc = (z == 0) ? 0.18033688011112042f : 1.0f;
    if (z < 2)
        gemm_body<0, 4>(A, W, bias, (z == 0) ? (void*)Qhp : (void*)Khp, As, Ws,
                        bx, by, osc);
    else
        gemm_body<2, 4>(A, W, bias, (void*)Vtp, As, Ws, bx, by, 1.0f);
}

__global__ __launch_bounds__(256) void gemm_out(
    const unsigned short* __restrict__ ab, const unsigned short* __restrict__ Wob,
    const float* __restrict__ bo, float* __restrict__ outp)
{
    __shared__ __align__(16) unsigned short As[3 * 128 * 32];   // 24 KB tbuf
    __shared__ __align__(16) unsigned short Ws[3 * 128 * 32];   // 24 KB tbuf
    // 128-wide N tile: grid 8x32 = 256 blocks; bijective XCD swizzle
    // (32-chunks/XCD): A-panel (1 MB) + full Wo (2 MB) fit one L2.
    int flat = blockIdx.x + (blockIdx.y << 3);
    int w = (flat & 7) * 32 + (flat >> 3);
    int bx = w & 7, by = w >> 3;
    gemm_body<3, 4>(ab, Wob, bo, (void*)outp, As, Ws, bx, by, 1.0f);
}

// --------------------------- flash attention --------------------------------
// One 64-q chunk per block. Wave w = (qh=w&1, kh=w>>1): 32 queries x 32 keys
// per tile -> each wave reads only its K half (2 groups) and V granule half
// (kh*4+kg): 8 ds_reads/wave-tile, block-tile LDS reads 32KB (was 64KB).
// Cross-kh O/l combine once per block via Ks-as-scratch. Longest-first qc
// map; K tbuf (depth-2) + V dbuf (depth-1) = 40KB; raw s_barrier + counted
// vmcnt(2); unroll-6; per-wave allm bitmask; Q pre-scaled; denom on matrix
// pipe; launch_bounds(256,4) pins VGPR<=128 for 4 blocks/CU.
__global__ __launch_bounds__(256, 4) void attn_fwd(
    const unsigned short* __restrict__ Qh, const unsigned short* __restrict__ Kh,
    const unsigned short* __restrict__ Vt, const int* __restrict__ mask,
    const int* __restrict__ causal_p, unsigned short* __restrict__ attnout)
{
    __shared__ __align__(16) unsigned short Ks[3][64 * 64];   // 24 KB (+scratch)
    __shared__ __align__(16) unsigned short Vs[2][64 * 64];   // 16 KB

    const int tid = threadIdx.x;
    const int lane = tid & 63, wave = tid >> 6;
    const int qh = wave & 1, kh = wave >> 1;
    const int bh = blockIdx.x;
    const int y = blockIdx.y, y0 = y & 7, j4 = y >> 3;
    // longest-first, per-CU-balanced qc map (bijective over 0..31)
    const int qc = (j4 == 0) ? (31 - y0) : (j4 == 1) ? (16 + y0)
                 : (j4 == 2) ? (15 - y0) : y0;
    const int b = bh >> 4, h = bh & 15;
    const int causal = *causal_p;
    const int r16 = lane & 15, kg = lane >> 4;

    const unsigned short* Qb = Qh + (size_t)b * T_ * D_MODEL + h * 64;
    const unsigned short* Kb = Kh + (size_t)b * T_ * D_MODEL + h * 64;
    const unsigned short* Vb = Vt + (size_t)bh * 64 * T_;
    const int* mb = mask + b * T_;

    const int nT = causal ? (qc + 1) : 32;

    // per-wave uniform bitmask: bit t = tile t fully unmasked (no LDS, no sync)
    unsigned allm = 0;
    for (int tt = 0; tt < nT; ++tt) {
        unsigned long long m = __ballot(mb[tt * 64 + lane] != 0);
        if (m == ~0ull) allm |= (1u << tt);
    }

    // Q fragments for both 16-q groups of this wave's 32-q half.
    // g-group queries: qc*64 + qh*32 + g*16 + r16.
    bf16x8 qf0[2], qf1[2];
    #pragma unroll
    for (int g = 0; g < 2; ++g) {
        const unsigned short* qrow =
            Qb + (size_t)(qc * 64 + qh * 32 + g * 16 + r16) * D_MODEL;
        qf0[g] = *(const bf16x8*)(qrow + kg * 8);
        qf1[g] = *(const bf16x8*)(qrow + 32 + kg * 8);
    }

    // all-ones B-frag for the denominator MFMA
    union { unsigned u[4]; bf16x8 v; } onef;
    onef.u[0] = onef.u[1] = onef.u[2] = onef.u[3] = 0x3f803f80u;

    f32x4 lacc[2] = {(f32x4){0, 0, 0, 0}, (f32x4){0, 0, 0, 0}};
    f32x4 o[2][4];
    #pragma unroll
    for (int g = 0; g < 2; ++g)
        #pragma unroll
        for (int f = 0; f < 4; ++f) o[g][f] = (f32x4){0, 0, 0, 0};

    // hoisted staging addresses (tile t adds t*64 rows on K / t*64 cols on V)
    const unsigned short* Kp[2]; const unsigned short* Vp[2];
    char* Kl[2]; char* Vl[2];
    #pragma unroll
    for (int j = 0; j < 2; ++j) {
        int si = j * 256 + tid;
        int row = si >> 3, cg = (si & 7) ^ (row & 7);
        Kp[j] = Kb + (size_t)row * D_MODEL + cg * 8;
        Vp[j] = Vb + (size_t)row * T_ + cg * 8;
        Kl[j] = (char*)Ks[0] + (j * 256 + wave * 64) * 16;
        Vl[j] = (char*)Vs[0] + (j * 256 + wave * 64) * 16;
    }
    auto stageK = [&](int buf, int t) {
        #pragma unroll
        for (int j = 0; j < 2; ++j)
            gload_lds16(Kp[j] + ((size_t)t << 16), Kl[j] + buf * 8192);  // t*64*1024
    };
    auto stageV = [&](int buf, int t) {
        #pragma unroll
        for (int j = 0; j < 2; ++j)
            gload_lds16(Vp[j] + (t << 6), Vl[j] + buf * 8192);           // t*64
    };

    // one tile iteration; KB (0..2) / VB (0..1) compile-time in main loop.
#define TILE_ITER(KB, VB)                                                      \
    {                                                                          \
        if (t + 1 < nT) asm volatile("s_waitcnt vmcnt(2)" ::: "memory");       \
        else            asm volatile("s_waitcnt vmcnt(0)" ::: "memory");       \
        __builtin_amdgcn_s_barrier();                                          \
        __builtin_amdgcn_sched_barrier(0);                                     \
        if (t + 1 < nT) stageV(((VB) + 1) & 1, t + 1);   /* V first */         \
        if (t + 2 < nT) stageK(((KB) + 2) % 3, t + 2);   /* then K  */         \
        const unsigned short* Kst = Ks[KB];                                    \
        const unsigned short* Vst = Vs[VB];                                    \
        const bool diag = causal && (t == qc);                                 \
        f32x4 sv[2][2];                                                        \
        __builtin_amdgcn_s_setprio(1);                                         \
        _Pragma("unroll")                                                      \
        for (int c = 0; c < 2; ++c) {                                          \
            int key = kh * 32 + c * 16 + r16;                                  \
            bf16x8 kf0 = *(const bf16x8*)(Kst + key * 64 + ((kg ^ (key & 7)) * 8));       \
            bf16x8 kf1 = *(const bf16x8*)(Kst + key * 64 + (((4 + kg) ^ (key & 7)) * 8)); \
            _Pragma("unroll")                                                  \
            for (int g = 0; g < 2; ++g) {                                      \
                f32x4 z = (f32x4){0, 0, 0, 0};                                 \
                z = MFMA(kf0, qf0[g], z);                                      \
                z = MFMA(kf1, qf1[g], z);                                      \
                sv[c][g] = z;                                                  \
            }                                                                  \
        }                                                                      \
        __builtin_amdgcn_s_setprio(0);                                         \
        float pv[2][2][4];                                                     \
        if (!diag && ((allm >> t) & 1)) {                                      \
            _Pragma("unroll")                                                  \
            for (int c = 0; c < 2; ++c)                                        \
                _Pragma("unroll")                                              \
                for (int g = 0; g < 2; ++g)                                    \
                    _Pragma("unroll")                                          \
                    for (int r = 0; r < 4; ++r)                                \
                        pv[c][g][r] = __builtin_amdgcn_exp2f(sv[c][g][r]);     \
        } else {                                                               \
            unsigned long long km = __ballot(mb[t * 64 + lane] != 0);          \
            _Pragma("unroll")                                                  \
            for (int c = 0; c < 2; ++c) {                                      \
                unsigned mc = (unsigned)(km >> (kh * 32 + c * 16));            \
                _Pragma("unroll")                                              \
                for (int g = 0; g < 2; ++g) {                                  \
                    int limg = qh * 32 + g * 16 + r16;                         \
                    _Pragma("unroll")                                          \
                    for (int r = 0; r < 4; ++r) {                              \
                        int kbit = kg * 4 + r;                                 \
                        int klim = kh * 32 + c * 16 + kbit;                    \
                        bool ok = ((mc >> kbit) & 1) && (!diag || (klim <= limg)); \
                        pv[c][g][r] = ok ? __builtin_amdgcn_exp2f(sv[c][g][r]) : 0.f; \
                    }                                                          \
                }                                                              \
            }                                                                  \
        }                                                                      \
        union pk_t { unsigned u[4]; bf16x8 v; };                               \
        pk_t pa[2];                                                            \
        _Pragma("unroll")                                                      \
        for (int g = 0; g < 2; ++g)                                            \
            _Pragma("unroll")                                                  \
            for (int c = 0; c < 2; ++c) {                                      \
                pa[g].u[c * 2]     = pk2(pv[c][g][0], pv[c][g][1]);            \
                pa[g].u[c * 2 + 1] = pk2(pv[c][g][2], pv[c][g][3]);            \
            }                                                                  \
        __builtin_amdgcn_s_setprio(1);                                         \
        lacc[0] = MFMA(pa[0].v, onef.v, lacc[0]);                              \
        lacc[1] = MFMA(pa[1].v, onef.v, lacc[1]);                              \
        _Pragma("unroll")                                                      \
        for (int f = 0; f < 4; ++f) {                                          \
            int row = f * 16 + r16;                                            \
            int rx = row & 7;                                                  \
            int gg = kh * 4 + kg;    /* this wave's key-half granules */       \
            bf16x8 vf = *(const bf16x8*)(Vst + row * 64 + ((gg ^ rx) * 8));    \
            o[0][f] = MFMA(pa[0].v, vf, o[0][f]);                              \
            o[1][f] = MFMA(pa[1].v, vf, o[1][f]);                              \
        }                                                                      \
        __builtin_amdgcn_s_setprio(0);                                         \
    }

    // prologue: K0,V0 staged; K1 if it exists; sync drains all
    stageK(0, 0);
    stageV(0, 0);
    if (nT > 1) stageK(1, 1);
    __syncthreads();
    int t = 0;
    while (t + 6 <= nT) {           // main: unrolled 6 (K%3 x V%2 period)
        TILE_ITER(0, 0); ++t;
        TILE_ITER(1, 1); ++t;
        TILE_ITER(2, 0); ++t;
        TILE_ITER(0, 1); ++t;
        TILE_ITER(1, 0); ++t;
        TILE_ITER(2, 1); ++t;
    }
    {                               // tail (<=5 tiles); t%6==0 here
        int kb = 0, vbuf = 0;
        for (; t < nT; ++t) {
            TILE_ITER(kb, vbuf);
            kb = (kb == 2) ? 0 : kb + 1;
            vbuf ^= 1;
        }
    }
#undef TILE_ITER

    // ---- cross-kh combine (once per block) via Ks-as-scratch ----
    // scratch layout: per qh: 32 rows x stride 68 f32 (2-way bank at worst);
    // l at sm[2*2176 + qh*32 + row].
    __syncthreads();                 // all waves done reading Ks/Vs
    float* sm = (float*)Ks;
    float* lsm = sm + 2 * 2176;
    if (kh == 1) {
        #pragma unroll
        for (int g = 0; g < 2; ++g) {
            #pragma unroll
            for (int r = 0; r < 4; ++r) {
                int row = g * 16 + kg * 4 + r;
                #pragma unroll
                for (int f = 0; f < 4; ++f)
                    sm[qh * 2176 + row * 68 + f * 16 + r16] = o[g][f][r];
                if (r16 == 0) lsm[qh * 32 + row] = lacc[g][r];
            }
        }
    }
    __syncthreads();
    if (kh == 0) {
        #pragma unroll
        for (int g = 0; g < 2; ++g) {
            #pragma unroll
            for (int r = 0; r < 4; ++r) {
                int row = g * 16 + kg * 4 + r;
                float l = lacc[g][r] + lsm[qh * 32 + row];
                float iv = (l > 0.f) ? 1.0f / l : 0.f;
                size_t base = ((size_t)(b * T_ + qc * 64 + qh * 32 + row))
                              * D_MODEL + h * 64;
                #pragma unroll
                for (int f = 0; f < 4; ++f) {
                    float v = o[g][f][r] + sm[qh * 2176 + row * 68 + f * 16 + r16];
                    attnout[base + f * 16 + r16] = f32_to_bf16(v * iv);
                }
            }
        }
    }
}

// --------------------------- launch -----------------------------------------
extern "C" void kernel_launch(void* const* d_in, const int* in_sizes, int n_in,
                              void* d_out, int out_size, void* d_ws, size_t ws_size,
                              hipStream_t stream) {
    const float* q  = (const float*)d_in[0];
    const float* k  = (const float*)d_in[1];
    const float* v  = (const float*)d_in[2];
    const float* Wq = (const float*)d_in[3];
    const float* bq = (const float*)d_in[4];
    const float* Wk = (const float*)d_in[5];
    const float* bk = (const float*)d_in[6];
    const float* Wv = (const float*)d_in[7];
    const float* bv = (const float*)d_in[8];
    const float* Wo = (const float*)d_in[9];
    const float* bo = (const float*)d_in[10];
    const int* mask   = (const int*)d_in[11];
    const int* causal = (const int*)d_in[12];

    const size_t SZ_TOK = (size_t)M_TOK * D_MODEL;   // 4M elems
    const size_t SZ_W   = (size_t)D_MODEL * D_MODEL; // 1M elems

    unsigned short* qb  = (unsigned short*)d_ws;
    unsigned short* kb  = qb  + SZ_TOK;
    unsigned short* vb  = kb  + SZ_TOK;
    unsigned short* Wqb = vb  + SZ_TOK;
    unsigned short* Wkb = Wqb + SZ_W;
    unsigned short* Wvb = Wkb + SZ_W;
    unsigned short* Wob = Wvb + SZ_W;
    unsigned short* Qhp = Wob + SZ_W;
    unsigned short* Khp = Qhp + SZ_TOK;
    unsigned short* Vtp = Khp + SZ_TOK;
    unsigned short* ab  = Vtp + SZ_TOK;              // 64 MB total

    cvt_all<<<16384, 256, 0, stream>>>(q, k, v, Wq, Wk, Wv, Wo, (ushort4*)qb);

    gemm_qkv<<<dim3(D_MODEL / 128, M_TOK / 128, 3), 256, 0, stream>>>(
        qb, kb, vb, Wqb, Wkb, Wvb, bq, bk, bv, Qhp, Khp, Vtp);

    attn_fwd<<<dim3(32, 32), 256, 0, stream>>>(Qhp, Khp, Vtp, mask, causal, ab);

    gemm_out<<<dim3(D_MODEL / 128, M_TOK / 128), 256, 0, stream>>>(ab, Wob, bo,
                                                                   (float*)d_out);
}

// Round 11
// 212.698 us; speedup vs baseline: 1.0334x; 1.0334x over previous
//
#include <hip/hip_runtime.h>
#include <cstdint>
#include <cstddef>

// ---------------------------------------------------------------------------
// MHA: out = softmax(causal(mask((XWq)(XWk)^T/8))) (XWv) Wo + biases
// B=2, T=2048, D=1024, H=16, dk=64. bf16 MFMA, fp32 accumulate.
// R18 (consolidation): attn experiments R14/R16/R17 all failed their
//   falsifiers (QBLK=128: occupancy loss; split-KV: +write traffic, no gain;
//   q/k-half split: VGPR clamp spills). attn_fwd REVERTED to R13 verbatim
//   (best measured 40.8us). Pivot to gemm_out: R9 made it 128-wide N ->
//   grid 256 = 1 block/CU = 1 wave/SIMD (no latency hiding). Back to
//   NT16=2 (64-wide N): grid 16x32=512 = 2 blocks/CU. Pipeline waitcnt
//   parameterized (stage = AL+WL loads: vmcnt(3) @NT16=2, vmcnt(4) @NT16=4).
//   gemm_qkv/cvt frozen at R9/R10 structure.
// ---------------------------------------------------------------------------

typedef __bf16 bf16x8 __attribute__((ext_vector_type(8)));
typedef float f32x4 __attribute__((ext_vector_type(4)));

#define MFMA(a, b, c) __builtin_amdgcn_mfma_f32_16x16x32_bf16((a), (b), (c), 0, 0, 0)

static constexpr int D_MODEL = 1024;
static constexpr int T_ = 2048;
static constexpr int M_TOK = 4096;   // B*T

__device__ __forceinline__ unsigned short f32_to_bf16(float f) {   // RNE
    union { float f; uint32_t u; } v; v.f = f;
    uint32_t u = v.u;
    uint32_t r = u + 0x7fffu + ((u >> 16) & 1u);
    return (unsigned short)(r >> 16);
}
// pack two f32 -> bf16x2 (low = a). Compiler emits v_cvt_pk_bf16_f32 (RNE).
__device__ __forceinline__ unsigned pk2(float a, float b) {
    union { __bf16 h[2]; unsigned u; } z;
    z.h[0] = (__bf16)a; z.h[1] = (__bf16)b;
    return z.u;
}

typedef __attribute__((address_space(1))) void* as1_ptr;
typedef __attribute__((address_space(3))) void* as3_ptr;
__device__ __forceinline__ void gload_lds16(const void* g, void* l) {
    // lane's 16B land at (wave-uniform l) + lane*16
    __builtin_amdgcn_global_load_lds((as1_ptr)(void*)g, (as3_ptr)l, 16, 0, 0);
}

// sigma: actual key (within 64) -> storage index matching PV MFMA k-slots.
__device__ __forceinline__ int keyperm(int k) {
    return (k & 32) | ((k & 12) << 1) | ((k & 16) >> 2) | (k & 3);
}

// --------------------------- fused fp32 -> bf16 convert ---------------------
// dst (float4 units): q[0,1M) k[1M,2M) v[2M,3M) Wq Wk Wv Wo [3M..4M)
__global__ __launch_bounds__(256) void cvt_all(
    const float* __restrict__ q, const float* __restrict__ k,
    const float* __restrict__ v, const float* __restrict__ wq,
    const float* __restrict__ wk, const float* __restrict__ wv,
    const float* __restrict__ wo, ushort4* __restrict__ dst) {
    int i = blockIdx.x * blockDim.x + threadIdx.x;
    constexpr int R = 1 << 20;        // 1M float4 per token tensor
    const float* s;
    int idx;
    if (i < 3 * R) {
        s = (i < R) ? q : (i < 2 * R) ? k : v;
        idx = i & (R - 1);
    } else {
        int j = i - 3 * R;
        int w = j >> 18;
        s = (w == 0) ? wq : (w == 1) ? wk : (w == 2) ? wv : wo;
        idx = j & ((1 << 18) - 1);
    }
    float4 f = ((const float4*)s)[idx];
    ushort4 o;
    o.x = (unsigned short)f32_to_bf16(f.x); o.y = (unsigned short)f32_to_bf16(f.y);
    o.z = (unsigned short)f32_to_bf16(f.z); o.w = (unsigned short)f32_to_bf16(f.w);
    dst[i] = o;
}

// --------------------------- GEMM: C = A @ W^T + bias -----------------------
// Tile 128 x (NT16*32), BK=32, 4 waves 2x2, global_load_lds(16B).
// Triple-buffered LDS, raw s_barrier + counted vmcnt (= loads/stage so the
// wait retires exactly the oldest stage; one stage stays in flight across
// the barrier). Granule swizzle: physical g = logical ^ ((row>>1)&3).
// MODE 0: bf16 row-major [M][1024] (Q,K; SWAPPED epilogue -> ushort4 stores).
// MODE 2: bf16 [B][H][64][Tperm] (V; UNswapped, t sigma-permuted per 64-blk).
// MODE 3: f32 row-major [M][1024] (SWAPPED -> float4 stores).
// oscale: multiplies (acc + bias) -- used to pre-scale Q by log2(e)/sqrt(dk).
template<int MODE, int NT16>
__device__ __forceinline__ void gemm_body(
    const unsigned short* __restrict__ A, const unsigned short* __restrict__ W,
    const float* __restrict__ bias, void* __restrict__ outp,
    unsigned short* As, unsigned short* Ws, int bx, int by, float oscale)
{
    constexpr bool SWAP = (MODE != 2);
    constexpr int BKE = 32;                     // K elems per step
    constexpr int ASZ = 128 * BKE;              // ushorts per A buffer (8 KB)
    constexpr int WSZ = NT16 * 32 * BKE;        // ushorts per W buffer
    constexpr int AL = ASZ / (256 * 8);         // gloads/thread for A (=2)
    constexpr int WL = WSZ / (256 * 8);         // gloads/thread for W
    constexpr int NKS = D_MODEL / BKE;          // 32
    const int tid = threadIdx.x;
    const int lane = tid & 63, wave = tid >> 6;
    const int wm = wave >> 1, wn = wave & 1;
    const int r16 = lane & 15, kg = lane >> 4;
    const int m_blk = by * 128, n_blk = bx * (NT16 * 32);

    // hoisted staging addresses: source pre-swizzled, LDS dest linear
    const unsigned short* Ap[AL]; unsigned short* Albase[AL];
    #pragma unroll
    for (int j = 0; j < AL; ++j) {
        int si = j * 256 + tid;
        int row = si >> 2, p = si & 3, g = p ^ ((row >> 1) & 3);
        Ap[j] = A + (size_t)(m_blk + row) * D_MODEL + g * 8;
        Albase[j] = As + (j * 256 + wave * 64) * 8;   // wave-uniform base
    }
    const unsigned short* Wp[WL]; unsigned short* Wlbase[WL];
    #pragma unroll
    for (int j = 0; j < WL; ++j) {
        int si = j * 256 + tid;
        int row = si >> 2, p = si & 3, g = p ^ ((row >> 1) & 3);
        Wp[j] = W + (size_t)(n_blk + row) * D_MODEL + g * 8;
        Wlbase[j] = Ws + (j * 256 + wave * 64) * 8;
    }

    // hoisted (loop-invariant) ds_read offsets
    int aoff[4], woff[NT16];
    #pragma unroll
    for (int mt = 0; mt < 4; ++mt) {
        int row = wm * 64 + mt * 16 + r16;
        aoff[mt] = row * BKE + ((kg ^ ((row >> 1) & 3)) * 8);
    }
    #pragma unroll
    for (int nt = 0; nt < NT16; ++nt) {
        int row = wn * (NT16 * 16) + nt * 16 + r16;
        woff[nt] = row * BKE + ((kg ^ ((row >> 1) & 3)) * 8);
    }

    f32x4 acc[4][NT16];
    #pragma unroll
    for (int mt = 0; mt < 4; ++mt)
        #pragma unroll
        for (int nt = 0; nt < NT16; ++nt) acc[mt][nt] = (f32x4){0, 0, 0, 0};

    auto stage = [&](int bb, int k0) {
        #pragma unroll
        for (int j = 0; j < AL; ++j)
            gload_lds16(Ap[j] + k0, Albase[j] + bb * ASZ);
        #pragma unroll
        for (int j = 0; j < WL; ++j)
            gload_lds16(Wp[j] + k0, Wlbase[j] + bb * WSZ);
    };

    // prologue: two stages in flight
    stage(0, 0);
    stage(1, BKE);
    int cb = 0;                                 // compute buffer = ks % 3
    for (int ks = 0; ks < NKS; ++ks) {
        // wait ONLY for stage(ks) (issued 2 steps ago); stage(ks+1) stays in
        // flight across the barrier. Last iter: drain.
        if (ks + 1 < NKS) {
            if constexpr (AL + WL == 4)
                asm volatile("s_waitcnt vmcnt(4)" ::: "memory");
            else
                asm volatile("s_waitcnt vmcnt(3)" ::: "memory");
        } else {
            asm volatile("s_waitcnt vmcnt(0)" ::: "memory");
        }
        __builtin_amdgcn_s_barrier();           // raw: no compiler vmcnt drain
        __builtin_amdgcn_sched_barrier(0);      // ds_reads must not hoist above
        if (ks + 2 < NKS) {
            int sb = cb + 2; if (sb >= 3) sb -= 3;
            stage(sb, (ks + 2) * BKE);          // buf freed by compute(ks-1)
        }
        const unsigned short* Asb = As + cb * ASZ;
        const unsigned short* Wsb = Ws + cb * WSZ;
        bf16x8 af[4], wf[NT16];
        #pragma unroll
        for (int mt = 0; mt < 4; ++mt)
            af[mt] = *(const bf16x8*)(Asb + aoff[mt]);
        #pragma unroll
        for (int nt = 0; nt < NT16; ++nt)
            wf[nt] = *(const bf16x8*)(Wsb + woff[nt]);
        #pragma unroll
        for (int mt = 0; mt < 4; ++mt)
            #pragma unroll
            for (int nt = 0; nt < NT16; ++nt)
                acc[mt][nt] = SWAP ? MFMA(wf[nt], af[mt], acc[mt][nt])
                                   : MFMA(af[mt], wf[nt], acc[mt][nt]);
        cb = (cb == 2) ? 0 : cb + 1;
    }

    if (MODE == 2) {
        // UNswapped C/D: lane holds m = kg*4+r (t, consecutive), n = r16 fixed.
        #pragma unroll
        for (int nt = 0; nt < NT16; ++nt) {
            int n = n_blk + wn * (NT16 * 16) + nt * 16 + r16;
            float bn = bias[n];
            int hh = n >> 6, dki = n & 63;
            #pragma unroll
            for (int mt = 0; mt < 4; ++mt) {
                int m0 = m_blk + wm * 64 + mt * 16 + kg * 4;
                int mp = (m0 & ~63) | keyperm(m0 & 63);   // sigma within 64-blk
                int bb = mp >> 11, ti = mp & 2047;
                ushort4 pk;
                pk.x = f32_to_bf16((acc[mt][nt][0] + bn) * oscale);
                pk.y = f32_to_bf16((acc[mt][nt][1] + bn) * oscale);
                pk.z = f32_to_bf16((acc[mt][nt][2] + bn) * oscale);
                pk.w = f32_to_bf16((acc[mt][nt][3] + bn) * oscale);
                *(ushort4*)((unsigned short*)outp +
                    ((size_t)(bb * 16 + hh) * 64 + dki) * 2048 + ti) = pk;
            }
        }
    } else {
        // SWAPPED C/D: lane holds n = kg*4+r (consecutive), m = r16 fixed.
        #pragma unroll
        for (int nt = 0; nt < NT16; ++nt) {
            int n0 = n_blk + wn * (NT16 * 16) + nt * 16 + kg * 4;
            float4 bn4 = *(const float4*)(bias + n0);
            #pragma unroll
            for (int mt = 0; mt < 4; ++mt) {
                int m = m_blk + wm * 64 + mt * 16 + r16;
                if (MODE == 3) {
                    float4 st;
                    st.x = (acc[mt][nt][0] + bn4.x) * oscale;
                    st.y = (acc[mt][nt][1] + bn4.y) * oscale;
                    st.z = (acc[mt][nt][2] + bn4.z) * oscale;
                    st.w = (acc[mt][nt][3] + bn4.w) * oscale;
                    *(float4*)((float*)outp + (size_t)m * D_MODEL + n0) = st;
                } else {
                    ushort4 pk;
                    pk.x = f32_to_bf16((acc[mt][nt][0] + bn4.x) * oscale);
                    pk.y = f32_to_bf16((acc[mt][nt][1] + bn4.y) * oscale);
                    pk.z = f32_to_bf16((acc[mt][nt][2] + bn4.z) * oscale);
                    pk.w = f32_to_bf16((acc[mt][nt][3] + bn4.w) * oscale);
                    *(ushort4*)((unsigned short*)outp + (size_t)m * D_MODEL + n0) = pk;
                }
            }
        }
    }
}

__global__ __launch_bounds__(256) void gemm_qkv(
    const unsigned short* __restrict__ qb, const unsigned short* __restrict__ kb,
    const unsigned short* __restrict__ vb, const unsigned short* __restrict__ Wqb,
    const unsigned short* __restrict__ Wkb, const unsigned short* __restrict__ Wvb,
    const float* __restrict__ bq, const float* __restrict__ bk, const float* __restrict__ bv,
    unsigned short* __restrict__ Qhp, unsigned short* __restrict__ Khp,
    unsigned short* __restrict__ Vtp)
{
    __shared__ __align__(16) unsigned short As[3 * 128 * 32];   // 24 KB tbuf
    __shared__ __align__(16) unsigned short Ws[3 * 128 * 32];   // 24 KB tbuf
    // Bijective XCD swizzle (grid 8x32x3, nwg=768): contiguous 96-chunks/XCD.
    int flat = blockIdx.x + (blockIdx.y << 3) + (blockIdx.z << 8);
    int w = (flat & 7) * 96 + (flat >> 3);
    int bx = w & 7, by = (w >> 3) & 31, z = w >> 8;
    const unsigned short* A = (z == 0) ? qb : (z == 1) ? kb : vb;
    const unsigned short* W = (z == 0) ? Wqb : (z == 1) ? Wkb : Wvb;
    const float* bias = (z == 0) ? bq : (z == 1) ? bk : bv;
    // Q stored pre-scaled by log2(e)/sqrt(dk): attn computes exp2(s) direct.
    float osc = (z == 0) ? 0.18033688011112042f : 1.0f;
    if (z < 2)
        gemm_body<0, 4>(A, W, bias, (z == 0) ? (void*)Qhp : (void*)Khp, As, Ws,
                        bx, by, osc);
    else
        gemm_body<2, 4>(A, W, bias, (void*)Vtp, As, Ws, bx, by, 1.0f);
}

__global__ __launch_bounds__(256) void gemm_out(
    const unsigned short* __restrict__ ab, const unsigned short* __restrict__ Wob,
    const float* __restrict__ bo, float* __restrict__ outp)
{
    __shared__ __align__(16) unsigned short As[3 * 128 * 32];   // 24 KB tbuf
    __shared__ __align__(16) unsigned short Ws[3 * 64 * 32];    // 12 KB tbuf
    // 64-wide N tile: grid 16x32 = 512 blocks = 2 blocks/CU (R9's 128-wide
    // gave 256 blocks = 1/CU = 1 wave/SIMD -- no latency hiding). Bijective
    // XCD swizzle, 64-chunks/XCD: 4 A-panels (1MB) + full Wo (2MB) <= L2.
    int flat = blockIdx.x + (blockIdx.y << 4);
    int w = (flat & 7) * 64 + (flat >> 3);
    int bx = w & 15, by = w >> 4;
    gemm_body<3, 2>(ab, Wob, bo, (void*)outp, As, Ws, bx, by, 1.0f);
}

// --------------------------- flash attention --------------------------------
// (R13 verbatim -- best measured 40.8us.) One 64-q chunk per block (4 waves x
// 16 q). Longest-first per-CU-balanced qc map; K/V TRIPLE-buffered, raw
// s_barrier + counted vmcnt(4). Tile body instantiated with COMPILE-TIME
// buffer index (unroll-by-3 + tail): all LDS reads become base + offset:imm.
// P-pack via (__bf16) casts -> v_cvt_pk_bf16_f32. Q pre-scaled -> exp2
// direct; denom on the matrix pipe (lacc = MFMA(pa, ones)); setprio.
__global__ __launch_bounds__(256) void attn_fwd(
    const unsigned short* __restrict__ Qh, const unsigned short* __restrict__ Kh,
    const unsigned short* __restrict__ Vt, const int* __restrict__ mask,
    const int* __restrict__ causal_p, unsigned short* __restrict__ attnout)
{
    __shared__ __align__(16) unsigned short Ks[3][64 * 64];   // [key][dk] swz
    __shared__ __align__(16) unsigned short Vs[3][64 * 64];   // [dk][kperm] swz
    __shared__ unsigned long long kmS[32];                    // per-tile key mask

    const int tid = threadIdx.x;
    const int lane = tid & 63, wave = tid >> 6;
    const int bh = blockIdx.x;
    const int y = blockIdx.y, y0 = y & 7, j4 = y >> 3;
    // longest-first, per-CU-balanced qc map (bijective over 0..31)
    const int qc = (j4 == 0) ? (31 - y0) : (j4 == 1) ? (16 + y0)
                 : (j4 == 2) ? (15 - y0) : y0;
    const int b = bh >> 4, h = bh & 15;
    const int causal = *causal_p;
    const int r16 = lane & 15, kg = lane >> 4;

    const int q0 = qc * 64 + wave * 16;

    const unsigned short* Qb = Qh + (size_t)b * T_ * D_MODEL + h * 64;
    const unsigned short* Kb = Kh + (size_t)b * T_ * D_MODEL + h * 64;
    const unsigned short* Vb = Vt + (size_t)bh * 64 * T_;
    const int* mb = mask + b * T_;

    // precompute per-tile 64-bit key masks into LDS (wave w: tiles w, w+4, ..)
    for (int t = wave; t < 32; t += 4) {
        unsigned long long m = __ballot(mb[t * 64 + lane] != 0);
        if (lane == 0) kmS[t] = m;
    }

    // Q fragments (B-operand for S^T: lane holds Q[q0+r16][kg*8+j])
    bf16x8 qf0 = *(const bf16x8*)(Qb + (size_t)(q0 + r16) * D_MODEL + kg * 8);
    bf16x8 qf1 = *(const bf16x8*)(Qb + (size_t)(q0 + r16) * D_MODEL + 32 + kg * 8);

    // all-ones B-frag for the denominator MFMA
    union { unsigned u[4]; bf16x8 v; } onef;
    onef.u[0] = onef.u[1] = onef.u[2] = onef.u[3] = 0x3f803f80u;

    f32x4 lacc = (f32x4){0, 0, 0, 0};    // denom: lacc[r] = l for q = kg*4+r
    f32x4 o[4];
    #pragma unroll
    for (int f = 0; f < 4; ++f) o[f] = (f32x4){0, 0, 0, 0};
    const int lim = wave * 16 + r16;          // causal limit on diagonal tile

    const int nT = causal ? (qc + 1) : 32;

    // hoisted staging addresses (tile t adds t*64 rows on K / t*64 cols on V)
    const unsigned short* Kp[2]; const unsigned short* Vp[2];
    char* Kl[2]; char* Vl[2];
    #pragma unroll
    for (int j = 0; j < 2; ++j) {
        int si = j * 256 + tid;
        int row = si >> 3, cg = (si & 7) ^ (row & 7);
        Kp[j] = Kb + (size_t)row * D_MODEL + cg * 8;
        Vp[j] = Vb + (size_t)row * T_ + cg * 8;
        Kl[j] = (char*)Ks[0] + (j * 256 + wave * 64) * 16;
        Vl[j] = (char*)Vs[0] + (j * 256 + wave * 64) * 16;
    }
    auto stage = [&](int buf, int t) {
        #pragma unroll
        for (int j = 0; j < 2; ++j) {
            gload_lds16(Kp[j] + ((size_t)t << 16), Kl[j] + buf * 8192);  // t*64*1024
            gload_lds16(Vp[j] + (t << 6),          Vl[j] + buf * 8192);  // t*64
        }
    };

    // one tile iteration with COMPILE-TIME buffer index CB (t%3 == CB).
#define TILE_ITER(CB)                                                          \
    {                                                                          \
        if (t + 1 < nT) asm volatile("s_waitcnt vmcnt(4)" ::: "memory");       \
        else            asm volatile("s_waitcnt vmcnt(0)" ::: "memory");       \
        __builtin_amdgcn_s_barrier();                                          \
        __builtin_amdgcn_sched_barrier(0);                                     \
        if (t + 2 < nT) stage((CB + 2) % 3, t + 2);                            \
        const unsigned short* Kst = Ks[CB];                                    \
        const unsigned short* Vst = Vs[CB];                                    \
        const bool diag = causal && (t == qc);                                 \
        unsigned long long km = kmS[t];                                        \
        f32x4 s[4];                                                            \
        __builtin_amdgcn_s_setprio(1);                                         \
        _Pragma("unroll")                                                      \
        for (int c = 0; c < 4; ++c) {                                          \
            int key = c * 16 + r16;                                            \
            bf16x8 kf0 = *(const bf16x8*)(Kst + key * 64 + ((kg ^ (key & 7)) * 8));       \
            bf16x8 kf1 = *(const bf16x8*)(Kst + key * 64 + (((4 + kg) ^ (key & 7)) * 8)); \
            f32x4 z = (f32x4){0, 0, 0, 0};                                     \
            z = MFMA(kf0, qf0, z);                                             \
            z = MFMA(kf1, qf1, z);                                             \
            s[c] = z;                                                          \
        }                                                                      \
        __builtin_amdgcn_s_setprio(0);                                         \
        float pv[4][4];                                                        \
        if (!diag && km == ~0ull) {                                            \
            _Pragma("unroll")                                                  \
            for (int c = 0; c < 4; ++c)                                        \
                _Pragma("unroll")                                              \
                for (int r = 0; r < 4; ++r)                                    \
                    pv[c][r] = __builtin_amdgcn_exp2f(s[c][r]);                \
        } else {                                                               \
            _Pragma("unroll")                                                  \
            for (int c = 0; c < 4; ++c) {                                      \
                unsigned mc = (unsigned)(km >> (c * 16));                      \
                _Pragma("unroll")                                              \
                for (int r = 0; r < 4; ++r) {                                  \
                    int kbit = kg * 4 + r;                                     \
                    bool ok = ((mc >> kbit) & 1) && (!diag || (c * 16 + kbit <= lim)); \
                    pv[c][r] = ok ? __builtin_amdgcn_exp2f(s[c][r]) : 0.f;     \
                }                                                              \
            }                                                                  \
        }                                                                      \
        union pk_t { unsigned u[4]; bf16x8 v; };                               \
        pk_t pa[2];                                                            \
        _Pragma("unroll")                                                      \
        for (int c = 0; c < 4; ++c) {                                          \
            int half = (c & 1) * 2;                                            \
            pa[c >> 1].u[half]     = pk2(pv[c][0], pv[c][1]);                  \
            pa[c >> 1].u[half + 1] = pk2(pv[c][2], pv[c][3]);                  \
        }                                                                      \
        __builtin_amdgcn_s_setprio(1);                                         \
        lacc = MFMA(pa[0].v, onef.v, lacc);                                    \
        lacc = MFMA(pa[1].v, onef.v, lacc);                                    \
        _Pragma("unroll")                                                      \
        for (int f = 0; f < 4; ++f) {                                          \
            int row = f * 16 + r16;                                            \
            int rx = row & 7;                                                  \
            _Pragma("unroll")                                                  \
            for (int cp = 0; cp < 2; ++cp) {                                   \
                int g = cp * 4 + kg;                                           \
                bf16x8 vf = *(const bf16x8*)(Vst + row * 64 + ((g ^ rx) * 8)); \
                o[f] = MFMA(pa[cp].v, vf, o[f]);                               \
            }                                                                  \
        }                                                                      \
        __builtin_amdgcn_s_setprio(0);                                         \
    }

    // prologue: tiles 0,1 staged; sync drains them + the kmS ds_writes
    stage(0, 0);
    stage(1, 1);
    __syncthreads();
    int t = 0;
    while (t + 3 <= nT) {           // main: unrolled triples, CB compile-time
        TILE_ITER(0); ++t;
        TILE_ITER(1); ++t;
        TILE_ITER(2); ++t;
    }
    if (t < nT) { TILE_ITER(0); ++t; }      // tail (t multiple of 3 here)
    if (t < nT) { TILE_ITER(1); ++t; }
#undef TILE_ITER

    // ---- epilogue: normalize with lane-local denom, store [B,T,D] ----
    #pragma unroll
    for (int r = 0; r < 4; ++r) {
        float iv = (lacc[r] > 0.f) ? 1.0f / lacc[r] : 0.f;
        size_t base = ((size_t)(b * T_ + q0 + kg * 4 + r)) * D_MODEL + h * 64;
        #pragma unroll
        for (int f = 0; f < 4; ++f)
            attnout[base + f * 16 + r16] = f32_to_bf16(o[f][r] * iv);
    }
}

// --------------------------- launch -----------------------------------------
extern "C" void kernel_launch(void* const* d_in, const int* in_sizes, int n_in,
                              void* d_out, int out_size, void* d_ws, size_t ws_size,
                              hipStream_t stream) {
    const float* q  = (const float*)d_in[0];
    const float* k  = (const float*)d_in[1];
    const float* v  = (const float*)d_in[2];
    const float* Wq = (const float*)d_in[3];
    const float* bq = (const float*)d_in[4];
    const float* Wk = (const float*)d_in[5];
    const float* bk = (const float*)d_in[6];
    const float* Wv = (const float*)d_in[7];
    const float* bv = (const float*)d_in[8];
    const float* Wo = (const float*)d_in[9];
    const float* bo = (const float*)d_in[10];
    const int* mask   = (const int*)d_in[11];
    const int* causal = (const int*)d_in[12];

    const size_t SZ_TOK = (size_t)M_TOK * D_MODEL;   // 4M elems
    const size_t SZ_W   = (size_t)D_MODEL * D_MODEL; // 1M elems

    unsigned short* qb  = (unsigned short*)d_ws;
    unsigned short* kb  = qb  + SZ_TOK;
    unsigned short* vb  = kb  + SZ_TOK;
    unsigned short* Wqb = vb  + SZ_TOK;
    unsigned short* Wkb = Wqb + SZ_W;
    unsigned short* Wvb = Wkb + SZ_W;
    unsigned short* Wob = Wvb + SZ_W;
    unsigned short* Qhp = Wob + SZ_W;
    unsigned short* Khp = Qhp + SZ_TOK;
    unsigned short* Vtp = Khp + SZ_TOK;
    unsigned short* ab  = Vtp + SZ_TOK;              // 64 MB total

    cvt_all<<<16384, 256, 0, stream>>>(q, k, v, Wq, Wk, Wv, Wo, (ushort4*)qb);

    gemm_qkv<<<dim3(D_MODEL / 128, M_TOK / 128, 3), 256, 0, stream>>>(
        qb, kb, vb, Wqb, Wkb, Wvb, bq, bk, bv, Qhp, Khp, Vtp);

    attn_fwd<<<dim3(32, 32), 256, 0, stream>>>(Qhp, Khp, Vtp, mask, causal, ab);

    gemm_out<<<dim3(D_MODEL / 64, M_TOK / 128), 256, 0, stream>>>(ab, Wob, bo,
                                                                  (float*)d_out);
}